// Round 2
// baseline (391.568 us; speedup 1.0000x reference)
//
#include <hip/hip_runtime.h>
#include <stdint.h>

// ---------------------------------------------------------------------------
// PerformerAttention on MI355X (gfx950), bf16 MFMA pipeline.
// B=2 S=2048 D=512 H=8 dh=64.
// Round 4: swapped-QK attn (P[key][query] layout) -> direct nontemporal f4
// attn stores from registers, scalar rq/rli per lane, bf16 P-LDS with b64
// writes + b128 reads (half the LDS traffic); ksum fused into qkv K-epilogue
// (kernel removed). Double-buffered staging kept from round 3.
// ---------------------------------------------------------------------------

typedef __attribute__((ext_vector_type(8))) short short8;  // 8 x bf16
typedef __attribute__((ext_vector_type(4))) float f4;

#define MFMA(a, b, c) __builtin_amdgcn_mfma_f32_16x16x32_bf16(a, b, c, 0, 0, 0)

struct __align__(8) us4 { uint16_t a, b, c, d; };

__device__ __forceinline__ uint16_t f2bf(float f) {
  union { float f; uint32_t u; } v; v.f = f;
  uint32_t u = v.u;
  return (uint16_t)((u + 0x7fffu + ((u >> 16) & 1u)) >> 16);  // RNE
}
__device__ __forceinline__ float bf2f(uint16_t u) {
  union { uint32_t u; float f; } v; v.u = ((uint32_t)u) << 16; return v.f;
}
__device__ __forceinline__ us4 pack4(float4 v) {
  us4 r; r.a = f2bf(v.x); r.b = f2bf(v.y); r.c = f2bf(v.z); r.d = f2bf(v.w); return r;
}

// async global->LDS, 16B/lane. LDS dest = wave-uniform base + lane*16.
__device__ __forceinline__ void async16(const uint16_t* g, uint16_t* l) {
  __builtin_amdgcn_global_load_lds(
      (const __attribute__((address_space(1))) void*)g,
      (__attribute__((address_space(3))) void*)l, 16, 0, 0);
}

// ---------------------------------------------------------------------------
__global__ __launch_bounds__(256) void convert_kernel(
    const float* __restrict__ x, const float* __restrict__ Wq,
    const float* __restrict__ Wk, const float* __restrict__ Wv,
    const float* __restrict__ Wo, uint16_t* __restrict__ xb,
    uint16_t* __restrict__ W3, uint16_t* __restrict__ Wob) {
  int i = blockIdx.x * 256 + threadIdx.x;
  ((us4*)xb)[i] = pack4(((const float4*)x)[i]);
  if (i < 65536) {
    ((us4*)W3)[i]          = pack4(((const float4*)Wq)[i]);
    ((us4*)W3)[65536 + i]  = pack4(((const float4*)Wk)[i]);
    ((us4*)W3)[131072 + i] = pack4(((const float4*)Wv)[i]);
    ((us4*)Wob)[i]         = pack4(((const float4*)Wo)[i]);
  }
}

// ---------------------------------------------------------------------------
// Shared 128x128 bf16 gemm_bt mainloop: C[row,col] = sum_k A[row,k]*Bt[col,k].
// LDS tile [128 rows][32 k], rows of 4 x 16B chunks. Chunk stored at physical
// slot = chunk ^ (row&3) ^ ((row>>2)&3)  -> b128 frag reads are bank-uniform.
// Double-buffered: prefetch k0+32 into the other buffer before computing k0.
__device__ __forceinline__ void gemm_loop(
    const uint16_t* __restrict__ A, const uint16_t* __restrict__ Bt,
    int row0, int col0, uint16_t* A0, uint16_t* B0,
    uint16_t* A1, uint16_t* B1, f4 (&acc)[4][4]) {
  const int tid = threadIdx.x;
  const int w = tid >> 6, lane = tid & 63;
  const int c = lane & 15, quad = lane >> 4;
  const int wm = w >> 1, wn = w & 1;
  // staging: lane -> row (lane>>2) of 16-row chunk; fetch swizzled 16B slot
  const int srow = lane >> 2;
  const int sslot = ((lane & 3) ^ ((lane >> 2) & 3) ^ ((lane >> 4) & 3)) * 8;
  const uint16_t* Asrc = A + (size_t)(row0 + srow) * 512 + sslot;
  const uint16_t* Bsrc = Bt + (size_t)(col0 + srow) * 512 + sslot;
  // read swizzle for fragment row (..+c): pos = quad ^ (c&3) ^ (c>>2)
  const int posv = (quad ^ (c & 3) ^ (c >> 2)) * 8;
  // prologue: stage k0=0 into buffer 0
#pragma unroll
  for (int chh = 0; chh < 2; ++chh) {
    int ch = w * 2 + chh;  // 8 chunks of 16 rows
    async16(Asrc + (size_t)ch * 16 * 512, A0 + ch * 512);
    async16(Bsrc + (size_t)ch * 16 * 512, B0 + ch * 512);
  }
  __syncthreads();
  for (int k0 = 0; k0 < 512; k0 += 32) {
    const uint16_t* Ac = (k0 & 32) ? A1 : A0;
    const uint16_t* Bc = (k0 & 32) ? B1 : B0;
    if (k0 + 32 < 512) {  // prefetch next tile into the other buffer
      uint16_t* An = (k0 & 32) ? A0 : A1;
      uint16_t* Bn = (k0 & 32) ? B0 : B1;
#pragma unroll
      for (int chh = 0; chh < 2; ++chh) {
        int ch = w * 2 + chh;
        async16(Asrc + (size_t)ch * 16 * 512 + (k0 + 32), An + ch * 512);
        async16(Bsrc + (size_t)ch * 16 * 512 + (k0 + 32), Bn + ch * 512);
      }
    }
    short8 af[4], bfr[4];
#pragma unroll
    for (int mi = 0; mi < 4; ++mi)
      af[mi] = *(const short8*)&Ac[(wm * 64 + mi * 16 + c) * 32 + posv];
#pragma unroll
    for (int ni = 0; ni < 4; ++ni)
      bfr[ni] = *(const short8*)&Bc[(wn * 64 + ni * 16 + c) * 32 + posv];
#pragma unroll
    for (int mi = 0; mi < 4; ++mi)
#pragma unroll
      for (int ni = 0; ni < 4; ++ni)
        acc[mi][ni] = MFMA(af[mi], bfr[ni], acc[mi][ni]);
    __syncthreads();  // drains prefetch vmcnt AFTER compute; frees Ac/Bc
  }
}

// ---------------------------------------------------------------------------
__global__ __launch_bounds__(256) void qkv_gemm(
    const uint16_t* __restrict__ xb, const uint16_t* __restrict__ W3,
    const float* __restrict__ bq, const float* __restrict__ bk,
    const float* __restrict__ bv, uint16_t* __restrict__ Qb,
    uint16_t* __restrict__ Kb, uint16_t* __restrict__ Vt,
    float* __restrict__ rq) {
  // A0|B0|A1|B1 = 32 KB; Ct (epilogue-only) overlaps A1|B1 region.
  __shared__ __align__(16) uint16_t smem[25600];  // 51.2 KB
  uint16_t* A0 = smem;
  uint16_t* B0 = smem + 4096;
  uint16_t* A1 = smem + 8192;
  uint16_t* B1 = smem + 12288;
  uint16_t* Ct = smem + 8192;  // [128][136] V transpose staging (after loop)
  f4 acc[4][4] = {};
  const int row0 = blockIdx.y * 128, col0 = blockIdx.x * 128;
  gemm_loop(xb, W3, row0, col0, A0, B0, A1, B1, acc);
  const int tid = threadIdx.x, w = tid >> 6, lane = tid & 63;
  const int c = lane & 15, quad = lane >> 4;
  const int wm = w >> 1, wn = w & 1;
  const int r3 = col0 >> 9;  // 0=Q, 1=K, 2=V (block-uniform)
  if (r3 == 0) {
#pragma unroll
    for (int mi = 0; mi < 4; ++mi)
#pragma unroll
      for (int ni = 0; ni < 4; ++ni)
#pragma unroll
        for (int r = 0; r < 4; ++r) {
          int row = row0 + wm * 64 + mi * 16 + quad * 4 + r;
          int col = col0 + wn * 64 + ni * 16 + c;
          int o = col & 511;
          float v = acc[mi][ni][r] + bq[o];
          Qb[(size_t)row * 512 + o] = f2bf(fmaxf(v, 0.0f));
        }
  } else if (r3 == 1) {
    // K: relu-store + fused row-sum over this wave's 64-col head -> rq
    const int hh = ((col0 & 511) >> 6) + wn;  // head index 0..7
#pragma unroll
    for (int mi = 0; mi < 4; ++mi)
#pragma unroll
      for (int r = 0; r < 4; ++r) {
        int row = row0 + wm * 64 + mi * 16 + quad * 4 + r;
        float s = 0.f;
#pragma unroll
        for (int ni = 0; ni < 4; ++ni) {
          int col = col0 + wn * 64 + ni * 16 + c;
          int o = col & 511;
          float v = fmaxf(acc[mi][ni][r] + bk[o], 0.0f);
          Kb[(size_t)row * 512 + o] = f2bf(v);
          s += v;
        }
        s += __shfl_xor(s, 1, 16);
        s += __shfl_xor(s, 2, 16);
        s += __shfl_xor(s, 4, 16);
        s += __shfl_xor(s, 8, 16);
        if (c == 0) rq[(size_t)row * 8 + hh] = 1.0f / (s + 1e-6f);
      }
  } else {
    // V: bias, convert to bf16 into LDS [s_local][col_local] (+8 pad)
    // gemm_loop's final barrier passed -> safe to overwrite A1/B1 with Ct
#pragma unroll
    for (int mi = 0; mi < 4; ++mi)
#pragma unroll
      for (int ni = 0; ni < 4; ++ni)
#pragma unroll
        for (int r = 0; r < 4; ++r) {
          int sl = wm * 64 + mi * 16 + quad * 4 + r;
          int cl = wn * 64 + ni * 16 + c;
          int o = (col0 + cl) & 511;
          Ct[sl * 136 + cl] = f2bf(acc[mi][ni][r] + bv[o]);
        }
    __syncthreads();
    // cooperative transposed store: Vt[b*512 + ocol][2048], 16B per store
    const int b = row0 >> 11, s0 = row0 & 2047;
    const int cl = tid >> 1, half = tid & 1;
    const int ocol = (col0 - 1024) + cl;
    uint16_t* vdst = Vt + (size_t)(b * 512 + ocol) * 2048 + s0 + half * 64;
#pragma unroll
    for (int g = 0; g < 8; ++g) {
      union { short8 v; uint16_t e[8]; } o8;
#pragma unroll
      for (int jj = 0; jj < 8; ++jj)
        o8.e[jj] = Ct[(half * 64 + g * 8 + jj) * 136 + cl];
      *(short8*)(vdst + g * 8) = o8.v;
    }
  }
}

__global__ __launch_bounds__(256) void proj_gemm(
    const uint16_t* __restrict__ Ob, const uint16_t* __restrict__ Wob,
    const float* __restrict__ bo, float* __restrict__ out) {
  __shared__ __align__(16) uint16_t smem[16384];  // 32 KB: A0|B0|A1|B1
  uint16_t* A0 = smem;
  uint16_t* B0 = smem + 4096;
  uint16_t* A1 = smem + 8192;
  uint16_t* B1 = smem + 12288;
  f4 acc[4][4] = {};
  const int row0 = blockIdx.y * 128, col0 = blockIdx.x * 128;
  gemm_loop(Ob, Wob, row0, col0, A0, B0, A1, B1, acc);
  const int tid = threadIdx.x, w = tid >> 6, lane = tid & 63;
  const int c = lane & 15, quad = lane >> 4;
  const int wm = w >> 1, wn = w & 1;
#pragma unroll
  for (int mi = 0; mi < 4; ++mi)
#pragma unroll
    for (int ni = 0; ni < 4; ++ni)
#pragma unroll
      for (int r = 0; r < 4; ++r) {
        int row = row0 + wm * 64 + mi * 16 + quad * 4 + r;
        int col = col0 + wn * 64 + ni * 16 + c;
        out[(size_t)row * 512 + col] = acc[mi][ni][r] + bo[col];
      }
}

// ---------------------------------------------------------------------------
// attn: 1-D grid 512; block = 4 waves x 16 query rows (64-row q-tile).
// SWAPPED QK: s = mfma(K, Q) -> P[key = ni*16+quad*4+r][query = c].
//  - attn store: direct nontemporal f4 from regs (64B-coalesced per row)
//  - rq / 1/l are per-lane scalars (query = c); reduce = 2 shfl_xor
//  - PV A-frag redistribution via bf16 P-LDS [q=c][k], XOR-slotted:
//      write (per ni): b64 at slot (ni*2 + (quad>>1))^ (c&7), word (quad&1)*2
//      read  (per m):  b128 at slot (m*4 + quad) ^ (c&7)
// K/V LDS tiles 64x64 bf16 double-buffered, slot = chunk^(row&7).
__global__ __launch_bounds__(256) void attn_kernel(
    const uint16_t* __restrict__ Qb, const uint16_t* __restrict__ Kb,
    const uint16_t* __restrict__ Vt, const float* __restrict__ rq,
    float* __restrict__ attn, uint16_t* __restrict__ Ob) {
  __shared__ __align__(16) uint16_t Klds[2][64 * 64];
  __shared__ __align__(16) uint16_t Vlds[2][64 * 64];
  __shared__ __align__(16) uint16_t Pw[4][16 * 64];  // per-wave P bf16 [q][k]
  const int tid = threadIdx.x, w = tid >> 6, lane = tid & 63;
  const int c = lane & 15, quad = lane >> 4, c7 = c & 7;
  // XCD-affine decode: 2 heads per XCD slot, q-tiles cluster with their head
  const int bid = blockIdx.x;
  const int bh = (bid & 7) * 2 + ((bid >> 3) & 1);
  const int qt = bid >> 4;  // 0..31
  const int b = bh >> 3, h = bh & 7;
  const int n0 = qt * 64;
  const int rbase = b * 2048 + n0;
  // Q B-frags, resident: B[q=c][k=quad*8+j]
  const uint16_t* qptr = Qb + (size_t)(rbase + w * 16 + c) * 512 + h * 64 + quad * 8;
  short8 aq0 = *(const short8*)qptr;
  short8 aq1 = *(const short8*)(qptr + 32);
  const float rqv = rq[(size_t)(rbase + w * 16 + c) * 8 + h];
  // staging: lane -> row lane>>3 of 8-row chunk, swizzled 16B slot
  const int vsrow = lane >> 3;
  const int vslot = ((lane & 7) ^ vsrow) * 8;
  const uint16_t* Ksrc = Kb + (size_t)(b * 2048) * 512 + h * 64 + vslot;
  const uint16_t* Vsrc = Vt + (size_t)(bh * 64) * 2048 + vslot;

  // ---- pass 1: row sums of exp (K double-buffered) ----
  float lsum = 0.f;
#pragma unroll
  for (int chh = 0; chh < 2; ++chh) {
    int ch = w * 2 + chh;
    async16(Ksrc + (size_t)(ch * 8 + vsrow) * 512, Klds[0] + ch * 512);
  }
  __syncthreads();
  for (int kt = 0; kt < 32; ++kt) {
    const uint16_t* Kc = Klds[kt & 1];
    if (kt < 31) {  // prefetch next K tile into the other buffer
      uint16_t* Kn = Klds[(kt & 1) ^ 1];
#pragma unroll
      for (int chh = 0; chh < 2; ++chh) {
        int ch = w * 2 + chh;
        async16(Ksrc + (size_t)((kt + 1) * 64 + ch * 8 + vsrow) * 512,
                Kn + ch * 512);
      }
    }
#pragma unroll
    for (int ni = 0; ni < 4; ++ni) {
      const uint16_t* kp = &Kc[(ni * 16 + c) * 64];
      short8 bk0 = *(const short8*)(kp + ((quad ^ c7) * 8));
      short8 bk1 = *(const short8*)(kp + (((quad + 4) ^ c7) * 8));
      f4 s = {};
      s = MFMA(bk0, aq0, s);
      s = MFMA(bk1, aq1, s);
#pragma unroll
      for (int r = 0; r < 4; ++r) lsum += __expf(s[r] * rqv);
    }
    __syncthreads();  // drains prefetch AFTER compute
  }
  lsum += __shfl_xor(lsum, 16);
  lsum += __shfl_xor(lsum, 32);
  const float rli = 1.0f / lsum;

  // ---- pass 2: direct attn stores, accumulate O = P @ V ----
  f4 oacc[4] = {};
  float* arow = attn + ((size_t)bh * 2048 + n0 + w * 16 + c) * 2048;
  uint16_t* Pme = Pw[w];
#pragma unroll
  for (int chh = 0; chh < 2; ++chh) {
    int ch = w * 2 + chh;
    async16(Ksrc + (size_t)(ch * 8 + vsrow) * 512, Klds[0] + ch * 512);
    async16(Vsrc + (size_t)(ch * 8 + vsrow) * 2048, Vlds[0] + ch * 512);
  }
  __syncthreads();
  for (int kt = 0; kt < 32; ++kt) {
    const int cur = kt & 1;
    const uint16_t* Kc = Klds[cur];
    const uint16_t* Vc = Vlds[cur];
    if (kt < 31) {  // prefetch next K+V tiles into the other buffers
      uint16_t* Kn = Klds[cur ^ 1];
      uint16_t* Vn = Vlds[cur ^ 1];
#pragma unroll
      for (int chh = 0; chh < 2; ++chh) {
        int ch = w * 2 + chh;
        async16(Ksrc + (size_t)((kt + 1) * 64 + ch * 8 + vsrow) * 512,
                Kn + ch * 512);
        async16(Vsrc + (size_t)(ch * 8 + vsrow) * 2048 + (kt + 1) * 64,
                Vn + ch * 512);
      }
    }
#pragma unroll
    for (int ni = 0; ni < 4; ++ni) {
      const uint16_t* kp = &Kc[(ni * 16 + c) * 64];
      short8 bk0 = *(const short8*)(kp + ((quad ^ c7) * 8));
      short8 bk1 = *(const short8*)(kp + (((quad + 4) ^ c7) * 8));
      f4 s = {};
      s = MFMA(bk0, aq0, s);
      s = MFMA(bk1, aq1, s);
      f4 p;
#pragma unroll
      for (int r = 0; r < 4; ++r) p[r] = __expf(s[r] * rqv) * rli;
      // direct attn store: row = query (c), cols = kt*64 + ni*16 + quad*4
      __builtin_nontemporal_store(p, (f4*)&arow[kt * 64 + ni * 16 + quad * 4]);
      // pack to bf16 pairs, b64 write into swizzled P tile
      uint32_t q01 = (uint32_t)f2bf(p[0]) | ((uint32_t)f2bf(p[1]) << 16);
      uint32_t q23 = (uint32_t)f2bf(p[2]) | ((uint32_t)f2bf(p[3]) << 16);
      int slot_w = (ni * 2 + (quad >> 1)) ^ c7;
      uint32_t* wp = (uint32_t*)&Pme[c * 64 + slot_w * 8 + (quad & 1) * 4];
      wp[0] = q01;
      wp[1] = q23;
    }
    asm volatile("s_waitcnt lgkmcnt(0)" ::: "memory");  // wave's P visible
#pragma unroll
    for (int m = 0; m < 2; ++m) {
      short8 pa = *(const short8*)&Pme[c * 64 + (((m * 4 + quad) ^ c7) * 8)];
#pragma unroll
      for (int nj = 0; nj < 4; ++nj) {
        short8 bvv = *(const short8*)&Vc[(nj * 16 + c) * 64 +
                                         (((m * 4 + quad) ^ c7) * 8)];
        oacc[nj] = MFMA(pa, bvv, oacc[nj]);
      }
    }
    __syncthreads();  // drains prefetch AFTER compute
  }
#pragma unroll
  for (int nj = 0; nj < 4; ++nj)
#pragma unroll
    for (int r = 0; r < 4; ++r)
      Ob[(size_t)(rbase + w * 16 + quad * 4 + r) * 512 + h * 64 + nj * 16 + c] =
          f2bf(oacc[nj][r]);
}

// ---------------------------------------------------------------------------
extern "C" void kernel_launch(void* const* d_in, const int* in_sizes, int n_in,
                              void* d_out, int out_size, void* d_ws, size_t ws_size,
                              hipStream_t stream) {
  const float* x  = (const float*)d_in[0];
  const float* Wq = (const float*)d_in[1];
  const float* bq = (const float*)d_in[2];
  const float* Wk = (const float*)d_in[3];
  const float* bk = (const float*)d_in[4];
  const float* Wv = (const float*)d_in[5];
  const float* bv = (const float*)d_in[6];
  const float* Wo = (const float*)d_in[7];
  const float* bo = (const float*)d_in[8];

  float* out0 = (float*)d_out;                  // [2,2048,512] fp32
  float* attn = out0 + (size_t)2 * 2048 * 512;  // [2,8,2048,2048] fp32

  uint8_t* ws = (uint8_t*)d_ws;
  uint16_t* xb  = (uint16_t*)(ws);              // 4 MB
  uint16_t* W3  = (uint16_t*)(ws + 0x400000);   // 1.5 MB (Wq|Wk|Wv rows)
  uint16_t* Wob = (uint16_t*)(ws + 0x580000);   // 0.5 MB
  uint16_t* Qb  = (uint16_t*)(ws + 0x600000);   // 4 MB [4096][512]
  uint16_t* Kb  = (uint16_t*)(ws + 0xA00000);   // 4 MB [4096][512]
  uint16_t* Vt  = (uint16_t*)(ws + 0xE00000);   // 4 MB [b*512+h*64+d][2048]
  uint16_t* Ob  = (uint16_t*)(ws + 0x1200000);  // 4 MB [4096][512]
  float*    rq  = (float*)  (ws + 0x1600000);   // 128 KB [4096*8]

  convert_kernel<<<2048, 256, 0, stream>>>(x, Wq, Wk, Wv, Wo, xb, W3, Wob);
  qkv_gemm<<<dim3(12, 32), 256, 0, stream>>>(xb, W3, bq, bk, bv, Qb, Kb, Vt, rq);
  attn_kernel<<<512, 256, 0, stream>>>(Qb, Kb, Vt, rq, attn, Ob);
  proj_gemm<<<dim3(4, 32), 256, 0, stream>>>(Ob, Wob, bo, out0);
}

// Round 3
// 381.339 us; speedup vs baseline: 1.0268x; 1.0268x over previous
//
#include <hip/hip_runtime.h>
#include <stdint.h>

// ---------------------------------------------------------------------------
// PerformerAttention on MI355X (gfx950), bf16 MFMA pipeline.
// B=2 S=2048 D=512 H=8 dh=64.
// Round 5: key-split 8-wave attn blocks (512 thr): wave = (qsub, key-half).
// 2x TLP (16 waves/CU vs 8), per-wave serial chain halved (16 kt not 32).
// lsum cross-half LDS exchange; O cross-half LDS reduce. 80 KB dynamic LDS,
// exactly 2 blocks/CU. R4's swapped-QK, direct nt attn stores, bf16 P tile,
// fused ksum all kept.
// ---------------------------------------------------------------------------

typedef __attribute__((ext_vector_type(8))) short short8;  // 8 x bf16
typedef __attribute__((ext_vector_type(4))) float f4;

#define MFMA(a, b, c) __builtin_amdgcn_mfma_f32_16x16x32_bf16(a, b, c, 0, 0, 0)

struct __align__(8) us4 { uint16_t a, b, c, d; };

__device__ __forceinline__ uint16_t f2bf(float f) {
  union { float f; uint32_t u; } v; v.f = f;
  uint32_t u = v.u;
  return (uint16_t)((u + 0x7fffu + ((u >> 16) & 1u)) >> 16);  // RNE
}
__device__ __forceinline__ float bf2f(uint16_t u) {
  union { uint32_t u; float f; } v; v.u = ((uint32_t)u) << 16; return v.f;
}
__device__ __forceinline__ us4 pack4(float4 v) {
  us4 r; r.a = f2bf(v.x); r.b = f2bf(v.y); r.c = f2bf(v.z); r.d = f2bf(v.w); return r;
}

// async global->LDS, 16B/lane. LDS dest = wave-uniform base + lane*16.
__device__ __forceinline__ void async16(const uint16_t* g, uint16_t* l) {
  __builtin_amdgcn_global_load_lds(
      (const __attribute__((address_space(1))) void*)g,
      (__attribute__((address_space(3))) void*)l, 16, 0, 0);
}

// ---------------------------------------------------------------------------
__global__ __launch_bounds__(256) void convert_kernel(
    const float* __restrict__ x, const float* __restrict__ Wq,
    const float* __restrict__ Wk, const float* __restrict__ Wv,
    const float* __restrict__ Wo, uint16_t* __restrict__ xb,
    uint16_t* __restrict__ W3, uint16_t* __restrict__ Wob) {
  int i = blockIdx.x * 256 + threadIdx.x;
  ((us4*)xb)[i] = pack4(((const float4*)x)[i]);
  if (i < 65536) {
    ((us4*)W3)[i]          = pack4(((const float4*)Wq)[i]);
    ((us4*)W3)[65536 + i]  = pack4(((const float4*)Wk)[i]);
    ((us4*)W3)[131072 + i] = pack4(((const float4*)Wv)[i]);
    ((us4*)Wob)[i]         = pack4(((const float4*)Wo)[i]);
  }
}

// ---------------------------------------------------------------------------
// Shared 128x128 bf16 gemm_bt mainloop: C[row,col] = sum_k A[row,k]*Bt[col,k].
// LDS tile [128 rows][32 k], rows of 4 x 16B chunks. Chunk stored at physical
// slot = chunk ^ (row&3) ^ ((row>>2)&3)  -> b128 frag reads are bank-uniform.
// Double-buffered: prefetch k0+32 into the other buffer before computing k0.
__device__ __forceinline__ void gemm_loop(
    const uint16_t* __restrict__ A, const uint16_t* __restrict__ Bt,
    int row0, int col0, uint16_t* A0, uint16_t* B0,
    uint16_t* A1, uint16_t* B1, f4 (&acc)[4][4]) {
  const int tid = threadIdx.x;
  const int w = tid >> 6, lane = tid & 63;
  const int c = lane & 15, quad = lane >> 4;
  const int wm = w >> 1, wn = w & 1;
  // staging: lane -> row (lane>>2) of 16-row chunk; fetch swizzled 16B slot
  const int srow = lane >> 2;
  const int sslot = ((lane & 3) ^ ((lane >> 2) & 3) ^ ((lane >> 4) & 3)) * 8;
  const uint16_t* Asrc = A + (size_t)(row0 + srow) * 512 + sslot;
  const uint16_t* Bsrc = Bt + (size_t)(col0 + srow) * 512 + sslot;
  // read swizzle for fragment row (..+c): pos = quad ^ (c&3) ^ (c>>2)
  const int posv = (quad ^ (c & 3) ^ (c >> 2)) * 8;
  // prologue: stage k0=0 into buffer 0
#pragma unroll
  for (int chh = 0; chh < 2; ++chh) {
    int ch = w * 2 + chh;  // 8 chunks of 16 rows
    async16(Asrc + (size_t)ch * 16 * 512, A0 + ch * 512);
    async16(Bsrc + (size_t)ch * 16 * 512, B0 + ch * 512);
  }
  __syncthreads();
  for (int k0 = 0; k0 < 512; k0 += 32) {
    const uint16_t* Ac = (k0 & 32) ? A1 : A0;
    const uint16_t* Bc = (k0 & 32) ? B1 : B0;
    if (k0 + 32 < 512) {  // prefetch next tile into the other buffer
      uint16_t* An = (k0 & 32) ? A0 : A1;
      uint16_t* Bn = (k0 & 32) ? B0 : B1;
#pragma unroll
      for (int chh = 0; chh < 2; ++chh) {
        int ch = w * 2 + chh;
        async16(Asrc + (size_t)ch * 16 * 512 + (k0 + 32), An + ch * 512);
        async16(Bsrc + (size_t)ch * 16 * 512 + (k0 + 32), Bn + ch * 512);
      }
    }
    short8 af[4], bfr[4];
#pragma unroll
    for (int mi = 0; mi < 4; ++mi)
      af[mi] = *(const short8*)&Ac[(wm * 64 + mi * 16 + c) * 32 + posv];
#pragma unroll
    for (int ni = 0; ni < 4; ++ni)
      bfr[ni] = *(const short8*)&Bc[(wn * 64 + ni * 16 + c) * 32 + posv];
#pragma unroll
    for (int mi = 0; mi < 4; ++mi)
#pragma unroll
      for (int ni = 0; ni < 4; ++ni)
        acc[mi][ni] = MFMA(af[mi], bfr[ni], acc[mi][ni]);
    __syncthreads();  // drains prefetch vmcnt AFTER compute; frees Ac/Bc
  }
}

// ---------------------------------------------------------------------------
__global__ __launch_bounds__(256) void qkv_gemm(
    const uint16_t* __restrict__ xb, const uint16_t* __restrict__ W3,
    const float* __restrict__ bq, const float* __restrict__ bk,
    const float* __restrict__ bv, uint16_t* __restrict__ Qb,
    uint16_t* __restrict__ Kb, uint16_t* __restrict__ Vt,
    float* __restrict__ rq) {
  // A0|B0|A1|B1 = 32 KB; Ct (epilogue-only) overlaps A1|B1 region.
  __shared__ __align__(16) uint16_t smem[25600];  // 51.2 KB
  uint16_t* A0 = smem;
  uint16_t* B0 = smem + 4096;
  uint16_t* A1 = smem + 8192;
  uint16_t* B1 = smem + 12288;
  uint16_t* Ct = smem + 8192;  // [128][136] V transpose staging (after loop)
  f4 acc[4][4] = {};
  const int row0 = blockIdx.y * 128, col0 = blockIdx.x * 128;
  gemm_loop(xb, W3, row0, col0, A0, B0, A1, B1, acc);
  const int tid = threadIdx.x, w = tid >> 6, lane = tid & 63;
  const int c = lane & 15, quad = lane >> 4;
  const int wm = w >> 1, wn = w & 1;
  const int r3 = col0 >> 9;  // 0=Q, 1=K, 2=V (block-uniform)
  if (r3 == 0) {
#pragma unroll
    for (int mi = 0; mi < 4; ++mi)
#pragma unroll
      for (int ni = 0; ni < 4; ++ni)
#pragma unroll
        for (int r = 0; r < 4; ++r) {
          int row = row0 + wm * 64 + mi * 16 + quad * 4 + r;
          int col = col0 + wn * 64 + ni * 16 + c;
          int o = col & 511;
          float v = acc[mi][ni][r] + bq[o];
          Qb[(size_t)row * 512 + o] = f2bf(fmaxf(v, 0.0f));
        }
  } else if (r3 == 1) {
    // K: relu-store + fused row-sum over this wave's 64-col head -> rq
    const int hh = ((col0 & 511) >> 6) + wn;  // head index 0..7
#pragma unroll
    for (int mi = 0; mi < 4; ++mi)
#pragma unroll
      for (int r = 0; r < 4; ++r) {
        int row = row0 + wm * 64 + mi * 16 + quad * 4 + r;
        float s = 0.f;
#pragma unroll
        for (int ni = 0; ni < 4; ++ni) {
          int col = col0 + wn * 64 + ni * 16 + c;
          int o = col & 511;
          float v = fmaxf(acc[mi][ni][r] + bk[o], 0.0f);
          Kb[(size_t)row * 512 + o] = f2bf(v);
          s += v;
        }
        s += __shfl_xor(s, 1, 16);
        s += __shfl_xor(s, 2, 16);
        s += __shfl_xor(s, 4, 16);
        s += __shfl_xor(s, 8, 16);
        if (c == 0) rq[(size_t)row * 8 + hh] = 1.0f / (s + 1e-6f);
      }
  } else {
    // V: bias, convert to bf16 into LDS [s_local][col_local] (+8 pad)
    // gemm_loop's final barrier passed -> safe to overwrite A1/B1 with Ct
#pragma unroll
    for (int mi = 0; mi < 4; ++mi)
#pragma unroll
      for (int ni = 0; ni < 4; ++ni)
#pragma unroll
        for (int r = 0; r < 4; ++r) {
          int sl = wm * 64 + mi * 16 + quad * 4 + r;
          int cl = wn * 64 + ni * 16 + c;
          int o = (col0 + cl) & 511;
          Ct[sl * 136 + cl] = f2bf(acc[mi][ni][r] + bv[o]);
        }
    __syncthreads();
    // cooperative transposed store: Vt[b*512 + ocol][2048], 16B per store
    const int b = row0 >> 11, s0 = row0 & 2047;
    const int cl = tid >> 1, half = tid & 1;
    const int ocol = (col0 - 1024) + cl;
    uint16_t* vdst = Vt + (size_t)(b * 512 + ocol) * 2048 + s0 + half * 64;
#pragma unroll
    for (int g = 0; g < 8; ++g) {
      union { short8 v; uint16_t e[8]; } o8;
#pragma unroll
      for (int jj = 0; jj < 8; ++jj)
        o8.e[jj] = Ct[(half * 64 + g * 8 + jj) * 136 + cl];
      *(short8*)(vdst + g * 8) = o8.v;
    }
  }
}

__global__ __launch_bounds__(256) void proj_gemm(
    const uint16_t* __restrict__ Ob, const uint16_t* __restrict__ Wob,
    const float* __restrict__ bo, float* __restrict__ out) {
  __shared__ __align__(16) uint16_t smem[16384];  // 32 KB: A0|B0|A1|B1
  uint16_t* A0 = smem;
  uint16_t* B0 = smem + 4096;
  uint16_t* A1 = smem + 8192;
  uint16_t* B1 = smem + 12288;
  f4 acc[4][4] = {};
  const int row0 = blockIdx.y * 128, col0 = blockIdx.x * 128;
  gemm_loop(Ob, Wob, row0, col0, A0, B0, A1, B1, acc);
  const int tid = threadIdx.x, w = tid >> 6, lane = tid & 63;
  const int c = lane & 15, quad = lane >> 4;
  const int wm = w >> 1, wn = w & 1;
#pragma unroll
  for (int mi = 0; mi < 4; ++mi)
#pragma unroll
    for (int ni = 0; ni < 4; ++ni)
#pragma unroll
      for (int r = 0; r < 4; ++r) {
        int row = row0 + wm * 64 + mi * 16 + quad * 4 + r;
        int col = col0 + wn * 64 + ni * 16 + c;
        out[(size_t)row * 512 + col] = acc[mi][ni][r] + bo[col];
      }
}

// ---------------------------------------------------------------------------
// attn: grid 512 x 512 threads (8 waves). wave w = (qsub = w&3, kh = w>>2).
// Each wave: 16 queries (qsub*16 + c) x 1024 keys (half kh), 16 kt steps.
// Dynamic LDS 80 KB:
//   Klds [buf2][half2][64*64]  (32 KB)
//   Vlds [buf2][half2][64*64]  (32 KB)
//   Pw   [8 waves][16*64] bf16 (16 KB)
//   lsum_sh overlays Vlds buf1/half1 (free until pass2 it=0 prefetch);
//   Osh (64x64 f32) overlays Klds buf0 (free after loop).
__global__ __launch_bounds__(512) void attn_kernel(
    const uint16_t* __restrict__ Qb, const uint16_t* __restrict__ Kb,
    const uint16_t* __restrict__ Vt, const float* __restrict__ rq,
    float* __restrict__ attn, uint16_t* __restrict__ Ob) {
  extern __shared__ __align__(16) uint16_t smem[];
  uint16_t* Klds = smem;            // [buf*8192 + half*4096 + ...]
  uint16_t* Vlds = smem + 16384;
  uint16_t* Pw   = smem + 32768;    // [w*1024]
  float* lsum_sh = (float*)(Vlds + 12288);  // 128 floats, overlay
  const int tid = threadIdx.x, w = tid >> 6, lane = tid & 63;
  const int c = lane & 15, quad = lane >> 4, c7 = c & 7;
  const int qsub = w & 3, kh = w >> 2;
  // XCD-affine decode: 2 heads per XCD slot, q-tiles cluster with their head
  const int bid = blockIdx.x;
  const int bh = (bid & 7) * 2 + ((bid >> 3) & 1);
  const int qt = bid >> 4;  // 0..31
  const int b = bh >> 3, h = bh & 7;
  const int n0 = qt * 64;
  const int rbase = b * 2048 + n0;
  const int qrow = rbase + qsub * 16 + c;
  // Q B-frags, resident: B[q=c][k=quad*8+j]
  const uint16_t* qptr = Qb + (size_t)qrow * 512 + h * 64 + quad * 8;
  short8 aq0 = *(const short8*)qptr;
  short8 aq1 = *(const short8*)(qptr + 32);
  const float rqv = rq[(size_t)qrow * 8 + h];
  // staging: lane -> row lane>>3 of an 8-row group, pre-swizzled 16B slot
  const int vsrow = lane >> 3;
  const int vslot = ((lane & 7) ^ vsrow) * 8;

  // ---- pass 1: lsum over this wave's key half (K dbuf, both halves) ----
  // staging role: tile-half t1 = w&1, quarter q8 = w>>1; 2 async16/thread/it
  const int t1 = w & 1, q8 = w >> 1;
  const uint16_t* K1src =
      Kb + (size_t)(b * 2048 + t1 * 1024 + q8 * 8 + vsrow) * 512 + h * 64 + vslot;
  uint16_t* K1dst = Klds + t1 * 4096 + q8 * 512;
  float lsum = 0.f;
  async16(K1src, K1dst);
  async16(K1src + (size_t)32 * 512, K1dst + 2048);
  __syncthreads();
  for (int it = 0; it < 16; ++it) {
    const int cur = it & 1;
    if (it < 15) {
      const uint16_t* s = K1src + (size_t)(it + 1) * 64 * 512;
      uint16_t* d = K1dst + (cur ^ 1) * 8192;
      async16(s, d);
      async16(s + (size_t)32 * 512, d + 2048);
    }
    const uint16_t* Kc = Klds + cur * 8192 + kh * 4096;
#pragma unroll
    for (int ni = 0; ni < 4; ++ni) {
      const uint16_t* kp = &Kc[(ni * 16 + c) * 64];
      short8 bk0 = *(const short8*)(kp + ((quad ^ c7) * 8));
      short8 bk1 = *(const short8*)(kp + (((quad + 4) ^ c7) * 8));
      f4 s = {};
      s = MFMA(bk0, aq0, s);
      s = MFMA(bk1, aq1, s);
#pragma unroll
      for (int r = 0; r < 4; ++r) lsum += __expf(s[r] * rqv);
    }
    __syncthreads();
  }
  lsum += __shfl_xor(lsum, 16);
  lsum += __shfl_xor(lsum, 32);
  if (lane < 16) lsum_sh[w * 16 + c] = lsum;
  __syncthreads();
  const float rli =
      1.0f / (lsum_sh[qsub * 16 + c] + lsum_sh[(qsub + 4) * 16 + c]);

  // ---- pass 2: direct attn stores, O = P @ V over this wave's half ----
  // staging role: tile t2 = w&3 (K0,K1,V0,V1), pair = w>>2; 4 async16/it
  const int t2 = w & 3, pair = w >> 2;
  const bool isK = (t2 < 2);
  const uint16_t* Gsrc = isK
      ? Kb + (size_t)(b * 2048 + (t2 & 1) * 1024 + pair * 8 + vsrow) * 512 +
            h * 64 + vslot
      : Vt + (size_t)(bh * 64 + pair * 8 + vsrow) * 2048 + (t2 & 1) * 1024 +
            vslot;
  const size_t g_rr = isK ? (size_t)16 * 512 : (size_t)16 * 2048;
  const size_t g_it = isK ? (size_t)64 * 512 : (size_t)64;
  uint16_t* KV2dst = (isK ? Klds : Vlds) + (t2 & 1) * 4096 + pair * 512;
#pragma unroll
  for (int rr = 0; rr < 4; ++rr)
    async16(Gsrc + rr * g_rr, KV2dst + rr * 1024);
  __syncthreads();
  f4 oacc[4] = {};
  float* arow = attn + ((size_t)bh * 2048 + n0 + qsub * 16 + c) * 2048;
  uint16_t* Pme = Pw + w * 1024;
  const int colb = kh * 1024;
  for (int it = 0; it < 16; ++it) {
    const int cur = it & 1;
    if (it < 15) {  // prefetch next K/V tiles into the other buffer
      const uint16_t* s = Gsrc + (size_t)(it + 1) * g_it;
      uint16_t* d = KV2dst + (cur ^ 1) * 8192;
#pragma unroll
      for (int rr = 0; rr < 4; ++rr)
        async16(s + rr * g_rr, d + rr * 1024);
    }
    const uint16_t* Kc = Klds + cur * 8192 + kh * 4096;
    const uint16_t* Vc = Vlds + cur * 8192 + kh * 4096;
#pragma unroll
    for (int ni = 0; ni < 4; ++ni) {
      const uint16_t* kp = &Kc[(ni * 16 + c) * 64];
      short8 bk0 = *(const short8*)(kp + ((quad ^ c7) * 8));
      short8 bk1 = *(const short8*)(kp + (((quad + 4) ^ c7) * 8));
      f4 s = {};
      s = MFMA(bk0, aq0, s);
      s = MFMA(bk1, aq1, s);
      f4 p;
#pragma unroll
      for (int r = 0; r < 4; ++r) p[r] = __expf(s[r] * rqv) * rli;
      // direct attn store: row = query (c), cols = colb + it*64 + ni*16 + quad*4
      __builtin_nontemporal_store(
          p, (f4*)&arow[colb + it * 64 + ni * 16 + quad * 4]);
      // pack to bf16 pairs, b64 write into swizzled P tile
      uint32_t q01 = (uint32_t)f2bf(p[0]) | ((uint32_t)f2bf(p[1]) << 16);
      uint32_t q23 = (uint32_t)f2bf(p[2]) | ((uint32_t)f2bf(p[3]) << 16);
      int slot_w = (ni * 2 + (quad >> 1)) ^ c7;
      uint32_t* wp = (uint32_t*)&Pme[c * 64 + slot_w * 8 + (quad & 1) * 4];
      wp[0] = q01;
      wp[1] = q23;
    }
    asm volatile("s_waitcnt lgkmcnt(0)" ::: "memory");  // wave's P visible
#pragma unroll
    for (int m = 0; m < 2; ++m) {
      short8 pa = *(const short8*)&Pme[c * 64 + (((m * 4 + quad) ^ c7) * 8)];
#pragma unroll
      for (int nj = 0; nj < 4; ++nj) {
        short8 bvv = *(const short8*)&Vc[(nj * 16 + c) * 64 +
                                         (((m * 4 + quad) ^ c7) * 8)];
        oacc[nj] = MFMA(pa, bvv, oacc[nj]);
      }
    }
    __syncthreads();  // drains prefetch AFTER compute
  }
  // ---- combine O across key halves (Osh overlays Klds buf0, now dead) ----
  float* Osh = (float*)Klds;  // [64][64] f32 = 16 KB
  if (kh == 1) {
#pragma unroll
    for (int nj = 0; nj < 4; ++nj)
#pragma unroll
      for (int r = 0; r < 4; ++r)
        Osh[(qsub * 16 + quad * 4 + r) * 64 + nj * 16 + c] = oacc[nj][r];
  }
  __syncthreads();
  if (kh == 0) {
#pragma unroll
    for (int nj = 0; nj < 4; ++nj)
#pragma unroll
      for (int r = 0; r < 4; ++r) {
        float v =
            oacc[nj][r] + Osh[(qsub * 16 + quad * 4 + r) * 64 + nj * 16 + c];
        Ob[(size_t)(rbase + qsub * 16 + quad * 4 + r) * 512 + h * 64 +
           nj * 16 + c] = f2bf(v);
      }
  }
}

// ---------------------------------------------------------------------------
extern "C" void kernel_launch(void* const* d_in, const int* in_sizes, int n_in,
                              void* d_out, int out_size, void* d_ws, size_t ws_size,
                              hipStream_t stream) {
  const float* x  = (const float*)d_in[0];
  const float* Wq = (const float*)d_in[1];
  const float* bq = (const float*)d_in[2];
  const float* Wk = (const float*)d_in[3];
  const float* bk = (const float*)d_in[4];
  const float* Wv = (const float*)d_in[5];
  const float* bv = (const float*)d_in[6];
  const float* Wo = (const float*)d_in[7];
  const float* bo = (const float*)d_in[8];

  float* out0 = (float*)d_out;                  // [2,2048,512] fp32
  float* attn = out0 + (size_t)2 * 2048 * 512;  // [2,8,2048,2048] fp32

  uint8_t* ws = (uint8_t*)d_ws;
  uint16_t* xb  = (uint16_t*)(ws);              // 4 MB
  uint16_t* W3  = (uint16_t*)(ws + 0x400000);   // 1.5 MB (Wq|Wk|Wv rows)
  uint16_t* Wob = (uint16_t*)(ws + 0x580000);   // 0.5 MB
  uint16_t* Qb  = (uint16_t*)(ws + 0x600000);   // 4 MB [4096][512]
  uint16_t* Kb  = (uint16_t*)(ws + 0xA00000);   // 4 MB [4096][512]
  uint16_t* Vt  = (uint16_t*)(ws + 0xE00000);   // 4 MB [b*512+h*64+d][2048]
  uint16_t* Ob  = (uint16_t*)(ws + 0x1200000);  // 4 MB [4096][512]
  float*    rq  = (float*)  (ws + 0x1600000);   // 128 KB [4096*8]

  static bool attr_set = false;
  if (!attr_set) {
    hipFuncSetAttribute((const void*)attn_kernel,
                        hipFuncAttributeMaxDynamicSharedMemorySize, 81920);
    attr_set = true;
  }

  convert_kernel<<<2048, 256, 0, stream>>>(x, Wq, Wk, Wv, Wo, xb, W3, Wob);
  qkv_gemm<<<dim3(12, 32), 256, 0, stream>>>(xb, W3, bq, bk, bv, Qb, Kb, Vt, rq);
  attn_kernel<<<512, 512, 81920, stream>>>(Qb, Kb, Vt, rq, attn, Ob);
  proj_gemm<<<dim3(4, 32), 256, 0, stream>>>(Ob, Wob, bo, out0);
}

// Round 4
// 377.353 us; speedup vs baseline: 1.0377x; 1.0106x over previous
//
#include <hip/hip_runtime.h>
#include <stdint.h>

// ---------------------------------------------------------------------------
// PerformerAttention on MI355X (gfx950), bf16 MFMA pipeline.
// B=2 S=2048 D=512 H=8 dh=64.
// Round 6: GEMM grid-coverage fix. M-tile 128->64: qkv = 12x64 grid (768
// blocks, 3/CU uniform, 12 waves/CU vs 6), proj = 64x64 tiles, 8x64 grid
// (512 blocks, 2/CU vs half-GPU-idle). Templated gemm_tile<MT,NT>, same
// swizzled staging. Attn kernel unchanged from round 5.
// ---------------------------------------------------------------------------

typedef __attribute__((ext_vector_type(8))) short short8;  // 8 x bf16
typedef __attribute__((ext_vector_type(4))) float f4;

#define MFMA(a, b, c) __builtin_amdgcn_mfma_f32_16x16x32_bf16(a, b, c, 0, 0, 0)

struct __align__(8) us4 { uint16_t a, b, c, d; };

__device__ __forceinline__ uint16_t f2bf(float f) {
  union { float f; uint32_t u; } v; v.f = f;
  uint32_t u = v.u;
  return (uint16_t)((u + 0x7fffu + ((u >> 16) & 1u)) >> 16);  // RNE
}
__device__ __forceinline__ float bf2f(uint16_t u) {
  union { uint32_t u; float f; } v; v.u = ((uint32_t)u) << 16; return v.f;
}
__device__ __forceinline__ us4 pack4(float4 v) {
  us4 r; r.a = f2bf(v.x); r.b = f2bf(v.y); r.c = f2bf(v.z); r.d = f2bf(v.w); return r;
}

// async global->LDS, 16B/lane. LDS dest = wave-uniform base + lane*16.
__device__ __forceinline__ void async16(const uint16_t* g, uint16_t* l) {
  __builtin_amdgcn_global_load_lds(
      (const __attribute__((address_space(1))) void*)g,
      (__attribute__((address_space(3))) void*)l, 16, 0, 0);
}

// ---------------------------------------------------------------------------
__global__ __launch_bounds__(256) void convert_kernel(
    const float* __restrict__ x, const float* __restrict__ Wq,
    const float* __restrict__ Wk, const float* __restrict__ Wv,
    const float* __restrict__ Wo, uint16_t* __restrict__ xb,
    uint16_t* __restrict__ W3, uint16_t* __restrict__ Wob) {
  int i = blockIdx.x * 256 + threadIdx.x;
  ((us4*)xb)[i] = pack4(((const float4*)x)[i]);
  if (i < 65536) {
    ((us4*)W3)[i]          = pack4(((const float4*)Wq)[i]);
    ((us4*)W3)[65536 + i]  = pack4(((const float4*)Wk)[i]);
    ((us4*)W3)[131072 + i] = pack4(((const float4*)Wv)[i]);
    ((us4*)Wob)[i]         = pack4(((const float4*)Wo)[i]);
  }
}

// ---------------------------------------------------------------------------
// Templated MTxNT bf16 gemm_bt mainloop: C[row,col] = sum_k A[row,k]*Bt[col,k].
// LDS tiles [rows][32 k], rows of 4 x 16B chunks, physical slot =
// chunk ^ (row&3) ^ ((row>>2)&3) -> b128 frag reads bank-uniform.
// Double-buffered staging. 4 waves: wm = w&1 (MT/2 rows), wn = w>>1 (NT/2 cols).
template <int MT, int NT>
__device__ __forceinline__ void gemm_tile(
    const uint16_t* __restrict__ A, const uint16_t* __restrict__ Bt,
    int row0, int col0, uint16_t* A0, uint16_t* B0,
    uint16_t* A1, uint16_t* B1, f4 (&acc)[MT / 32][NT / 32]) {
  const int tid = threadIdx.x;
  const int w = tid >> 6, lane = tid & 63;
  const int c = lane & 15, quad = lane >> 4;
  const int wm = w & 1, wn = w >> 1;
  // staging: lane -> row (lane>>2) of a 16-row chunk; pre-swizzled 16B slot
  const int srow = lane >> 2;
  const int sslot = ((lane & 3) ^ ((lane >> 2) & 3) ^ ((lane >> 4) & 3)) * 8;
  const uint16_t* Asrc = A + (size_t)(row0 + srow) * 512 + sslot;
  const uint16_t* Bsrc = Bt + (size_t)(col0 + srow) * 512 + sslot;
  // read swizzle for fragment row (..+c): pos = quad ^ (c&3) ^ (c>>2)
  const int posv = (quad ^ (c & 3) ^ (c >> 2)) * 8;
  constexpr int ACH = MT / 16, BCH = NT / 16;  // 16-row chunks per tile
  auto stage = [&](uint16_t* Ad, uint16_t* Bd, int k0) {
#pragma unroll
    for (int i = 0; i < ACH / 4; ++i) {
      int ch = i * 4 + w;
      async16(Asrc + (size_t)ch * 16 * 512 + k0, Ad + ch * 512);
    }
#pragma unroll
    for (int i = 0; i < BCH / 4; ++i) {
      int ch = i * 4 + w;
      async16(Bsrc + (size_t)ch * 16 * 512 + k0, Bd + ch * 512);
    }
  };
  stage(A0, B0, 0);
  __syncthreads();
  for (int k0 = 0; k0 < 512; k0 += 32) {
    const uint16_t* Ac = (k0 & 32) ? A1 : A0;
    const uint16_t* Bc = (k0 & 32) ? B1 : B0;
    if (k0 + 32 < 512)  // prefetch next tile into the other buffer
      stage((k0 & 32) ? A0 : A1, (k0 & 32) ? B0 : B1, k0 + 32);
    short8 af[MT / 32], bfr[NT / 32];
#pragma unroll
    for (int mi = 0; mi < MT / 32; ++mi)
      af[mi] = *(const short8*)&Ac[(wm * (MT / 2) + mi * 16 + c) * 32 + posv];
#pragma unroll
    for (int ni = 0; ni < NT / 32; ++ni)
      bfr[ni] = *(const short8*)&Bc[(wn * (NT / 2) + ni * 16 + c) * 32 + posv];
#pragma unroll
    for (int mi = 0; mi < MT / 32; ++mi)
#pragma unroll
      for (int ni = 0; ni < NT / 32; ++ni)
        acc[mi][ni] = MFMA(af[mi], bfr[ni], acc[mi][ni]);
    __syncthreads();  // drains prefetch vmcnt AFTER compute; frees Ac/Bc
  }
}

// ---------------------------------------------------------------------------
// qkv: 64(M) x 128(N) tiles, grid (12, 64) = 768 blocks (3/CU uniform).
__global__ __launch_bounds__(256) void qkv_gemm(
    const uint16_t* __restrict__ xb, const uint16_t* __restrict__ W3,
    const float* __restrict__ bq, const float* __restrict__ bk,
    const float* __restrict__ bv, uint16_t* __restrict__ Qb,
    uint16_t* __restrict__ Kb, uint16_t* __restrict__ Vt,
    float* __restrict__ rq) {
  __shared__ __align__(16) uint16_t smem[12288];  // 24 KB: A0|B0|A1|B1
  uint16_t* A0 = smem;            // 64x32
  uint16_t* B0 = smem + 2048;     // 128x32
  uint16_t* A1 = smem + 6144;
  uint16_t* B1 = smem + 8192;
  uint16_t* Ct = smem;            // epilogue overlay: [64][136] = 8704 shorts
  f4 acc[2][4] = {};
  const int row0 = blockIdx.y * 64, col0 = blockIdx.x * 128;
  gemm_tile<64, 128>(xb, W3, row0, col0, A0, B0, A1, B1, acc);
  const int tid = threadIdx.x, w = tid >> 6, lane = tid & 63;
  const int c = lane & 15, quad = lane >> 4;
  const int wm = w & 1, wn = w >> 1;
  const int r3 = col0 >> 9;  // 0=Q, 1=K, 2=V (block-uniform)
  if (r3 == 0) {
#pragma unroll
    for (int mi = 0; mi < 2; ++mi)
#pragma unroll
      for (int ni = 0; ni < 4; ++ni)
#pragma unroll
        for (int r = 0; r < 4; ++r) {
          int row = row0 + wm * 32 + mi * 16 + quad * 4 + r;
          int col = col0 + wn * 64 + ni * 16 + c;
          int o = col & 511;
          float v = acc[mi][ni][r] + bq[o];
          Qb[(size_t)row * 512 + o] = f2bf(fmaxf(v, 0.0f));
        }
  } else if (r3 == 1) {
    // K: relu-store + fused row-sum over this wave's 64-col head -> rq
    const int hh = ((col0 & 511) >> 6) + wn;  // head index 0..7
#pragma unroll
    for (int mi = 0; mi < 2; ++mi)
#pragma unroll
      for (int r = 0; r < 4; ++r) {
        int row = row0 + wm * 32 + mi * 16 + quad * 4 + r;
        float s = 0.f;
#pragma unroll
        for (int ni = 0; ni < 4; ++ni) {
          int col = col0 + wn * 64 + ni * 16 + c;
          int o = col & 511;
          float v = fmaxf(acc[mi][ni][r] + bk[o], 0.0f);
          Kb[(size_t)row * 512 + o] = f2bf(v);
          s += v;
        }
        s += __shfl_xor(s, 1, 16);
        s += __shfl_xor(s, 2, 16);
        s += __shfl_xor(s, 4, 16);
        s += __shfl_xor(s, 8, 16);
        if (c == 0) rq[(size_t)row * 8 + hh] = 1.0f / (s + 1e-6f);
      }
  } else {
    // V: bias, convert to bf16 into LDS [s_local][col_local] (+8 pad);
    // gemm_tile's final barrier passed -> all LDS reads done, overlay safe
#pragma unroll
    for (int mi = 0; mi < 2; ++mi)
#pragma unroll
      for (int ni = 0; ni < 4; ++ni)
#pragma unroll
        for (int r = 0; r < 4; ++r) {
          int sl = wm * 32 + mi * 16 + quad * 4 + r;
          int cl = wn * 64 + ni * 16 + c;
          int o = (col0 + cl) & 511;
          Ct[sl * 136 + cl] = f2bf(acc[mi][ni][r] + bv[o]);
        }
    __syncthreads();
    // cooperative transposed store: Vt[b*512 + ocol][2048], 16B per store
    const int b = row0 >> 11, s0 = row0 & 2047;
    const int cl = tid >> 1, half = tid & 1;
    const int ocol = (col0 - 1024) + cl;
    uint16_t* vdst = Vt + (size_t)(b * 512 + ocol) * 2048 + s0 + half * 32;
#pragma unroll
    for (int g = 0; g < 4; ++g) {
      union { short8 v; uint16_t e[8]; } o8;
#pragma unroll
      for (int jj = 0; jj < 8; ++jj)
        o8.e[jj] = Ct[(half * 32 + g * 8 + jj) * 136 + cl];
      *(short8*)(vdst + g * 8) = o8.v;
    }
  }
}

// proj: 64(M) x 64(N) tiles, grid (8, 64) = 512 blocks (2/CU uniform).
__global__ __launch_bounds__(256) void proj_gemm(
    const uint16_t* __restrict__ Ob, const uint16_t* __restrict__ Wob,
    const float* __restrict__ bo, float* __restrict__ out) {
  __shared__ __align__(16) uint16_t smem[8192];  // 16 KB: A0|B0|A1|B1
  uint16_t* A0 = smem;
  uint16_t* B0 = smem + 2048;
  uint16_t* A1 = smem + 4096;
  uint16_t* B1 = smem + 6144;
  f4 acc[2][2] = {};
  const int row0 = blockIdx.y * 64, col0 = blockIdx.x * 64;
  gemm_tile<64, 64>(Ob, Wob, row0, col0, A0, B0, A1, B1, acc);
  const int tid = threadIdx.x, w = tid >> 6, lane = tid & 63;
  const int c = lane & 15, quad = lane >> 4;
  const int wm = w & 1, wn = w >> 1;
#pragma unroll
  for (int mi = 0; mi < 2; ++mi)
#pragma unroll
    for (int ni = 0; ni < 2; ++ni)
#pragma unroll
      for (int r = 0; r < 4; ++r) {
        int row = row0 + wm * 32 + mi * 16 + quad * 4 + r;
        int col = col0 + wn * 32 + ni * 16 + c;
        out[(size_t)row * 512 + col] = acc[mi][ni][r] + bo[col];
      }
}

// ---------------------------------------------------------------------------
// attn: grid 512 x 512 threads (8 waves). wave w = (qsub = w&3, kh = w>>2).
// Each wave: 16 queries (qsub*16 + c) x 1024 keys (half kh), 16 kt steps.
// Dynamic LDS 80 KB:
//   Klds [buf2][half2][64*64]  (32 KB)
//   Vlds [buf2][half2][64*64]  (32 KB)
//   Pw   [8 waves][16*64] bf16 (16 KB)
//   lsum_sh overlays Vlds buf1/half1 (free until pass2 it=0 prefetch);
//   Osh (64x64 f32) overlays Klds buf0 (free after loop).
__global__ __launch_bounds__(512) void attn_kernel(
    const uint16_t* __restrict__ Qb, const uint16_t* __restrict__ Kb,
    const uint16_t* __restrict__ Vt, const float* __restrict__ rq,
    float* __restrict__ attn, uint16_t* __restrict__ Ob) {
  extern __shared__ __align__(16) uint16_t smem[];
  uint16_t* Klds = smem;            // [buf*8192 + half*4096 + ...]
  uint16_t* Vlds = smem + 16384;
  uint16_t* Pw   = smem + 32768;    // [w*1024]
  float* lsum_sh = (float*)(Vlds + 12288);  // 128 floats, overlay
  const int tid = threadIdx.x, w = tid >> 6, lane = tid & 63;
  const int c = lane & 15, quad = lane >> 4, c7 = c & 7;
  const int qsub = w & 3, kh = w >> 2;
  // XCD-affine decode: 2 heads per XCD slot, q-tiles cluster with their head
  const int bid = blockIdx.x;
  const int bh = (bid & 7) * 2 + ((bid >> 3) & 1);
  const int qt = bid >> 4;  // 0..31
  const int b = bh >> 3, h = bh & 7;
  const int n0 = qt * 64;
  const int rbase = b * 2048 + n0;
  const int qrow = rbase + qsub * 16 + c;
  // Q B-frags, resident: B[q=c][k=quad*8+j]
  const uint16_t* qptr = Qb + (size_t)qrow * 512 + h * 64 + quad * 8;
  short8 aq0 = *(const short8*)qptr;
  short8 aq1 = *(const short8*)(qptr + 32);
  const float rqv = rq[(size_t)qrow * 8 + h];
  // staging: lane -> row lane>>3 of an 8-row group, pre-swizzled 16B slot
  const int vsrow = lane >> 3;
  const int vslot = ((lane & 7) ^ vsrow) * 8;

  // ---- pass 1: lsum over this wave's key half (K dbuf, both halves) ----
  // staging role: tile-half t1 = w&1, quarter q8 = w>>1; 2 async16/thread/it
  const int t1 = w & 1, q8 = w >> 1;
  const uint16_t* K1src =
      Kb + (size_t)(b * 2048 + t1 * 1024 + q8 * 8 + vsrow) * 512 + h * 64 + vslot;
  uint16_t* K1dst = Klds + t1 * 4096 + q8 * 512;
  float lsum = 0.f;
  async16(K1src, K1dst);
  async16(K1src + (size_t)32 * 512, K1dst + 2048);
  __syncthreads();
  for (int it = 0; it < 16; ++it) {
    const int cur = it & 1;
    if (it < 15) {
      const uint16_t* s = K1src + (size_t)(it + 1) * 64 * 512;
      uint16_t* d = K1dst + (cur ^ 1) * 8192;
      async16(s, d);
      async16(s + (size_t)32 * 512, d + 2048);
    }
    const uint16_t* Kc = Klds + cur * 8192 + kh * 4096;
#pragma unroll
    for (int ni = 0; ni < 4; ++ni) {
      const uint16_t* kp = &Kc[(ni * 16 + c) * 64];
      short8 bk0 = *(const short8*)(kp + ((quad ^ c7) * 8));
      short8 bk1 = *(const short8*)(kp + (((quad + 4) ^ c7) * 8));
      f4 s = {};
      s = MFMA(bk0, aq0, s);
      s = MFMA(bk1, aq1, s);
#pragma unroll
      for (int r = 0; r < 4; ++r) lsum += __expf(s[r] * rqv);
    }
    __syncthreads();
  }
  lsum += __shfl_xor(lsum, 16);
  lsum += __shfl_xor(lsum, 32);
  if (lane < 16) lsum_sh[w * 16 + c] = lsum;
  __syncthreads();
  const float rli =
      1.0f / (lsum_sh[qsub * 16 + c] + lsum_sh[(qsub + 4) * 16 + c]);

  // ---- pass 2: direct attn stores, O = P @ V over this wave's half ----
  // staging role: tile t2 = w&3 (K0,K1,V0,V1), pair = w>>2; 4 async16/it
  const int t2 = w & 3, pair = w >> 2;
  const bool isK = (t2 < 2);
  const uint16_t* Gsrc = isK
      ? Kb + (size_t)(b * 2048 + (t2 & 1) * 1024 + pair * 8 + vsrow) * 512 +
            h * 64 + vslot
      : Vt + (size_t)(bh * 64 + pair * 8 + vsrow) * 2048 + (t2 & 1) * 1024 +
            vslot;
  const size_t g_rr = isK ? (size_t)16 * 512 : (size_t)16 * 2048;
  const size_t g_it = isK ? (size_t)64 * 512 : (size_t)64;
  uint16_t* KV2dst = (isK ? Klds : Vlds) + (t2 & 1) * 4096 + pair * 512;
#pragma unroll
  for (int rr = 0; rr < 4; ++rr)
    async16(Gsrc + rr * g_rr, KV2dst + rr * 1024);
  __syncthreads();
  f4 oacc[4] = {};
  float* arow = attn + ((size_t)bh * 2048 + n0 + qsub * 16 + c) * 2048;
  uint16_t* Pme = Pw + w * 1024;
  const int colb = kh * 1024;
  for (int it = 0; it < 16; ++it) {
    const int cur = it & 1;
    if (it < 15) {  // prefetch next K/V tiles into the other buffer
      const uint16_t* s = Gsrc + (size_t)(it + 1) * g_it;
      uint16_t* d = KV2dst + (cur ^ 1) * 8192;
#pragma unroll
      for (int rr = 0; rr < 4; ++rr)
        async16(s + rr * g_rr, d + rr * 1024);
    }
    const uint16_t* Kc = Klds + cur * 8192 + kh * 4096;
    const uint16_t* Vc = Vlds + cur * 8192 + kh * 4096;
#pragma unroll
    for (int ni = 0; ni < 4; ++ni) {
      const uint16_t* kp = &Kc[(ni * 16 + c) * 64];
      short8 bk0 = *(const short8*)(kp + ((quad ^ c7) * 8));
      short8 bk1 = *(const short8*)(kp + (((quad + 4) ^ c7) * 8));
      f4 s = {};
      s = MFMA(bk0, aq0, s);
      s = MFMA(bk1, aq1, s);
      f4 p;
#pragma unroll
      for (int r = 0; r < 4; ++r) p[r] = __expf(s[r] * rqv) * rli;
      // direct attn store: row = query (c), cols = colb + it*64 + ni*16 + quad*4
      __builtin_nontemporal_store(
          p, (f4*)&arow[colb + it * 64 + ni * 16 + quad * 4]);
      // pack to bf16 pairs, b64 write into swizzled P tile
      uint32_t q01 = (uint32_t)f2bf(p[0]) | ((uint32_t)f2bf(p[1]) << 16);
      uint32_t q23 = (uint32_t)f2bf(p[2]) | ((uint32_t)f2bf(p[3]) << 16);
      int slot_w = (ni * 2 + (quad >> 1)) ^ c7;
      uint32_t* wp = (uint32_t*)&Pme[c * 64 + slot_w * 8 + (quad & 1) * 4];
      wp[0] = q01;
      wp[1] = q23;
    }
    asm volatile("s_waitcnt lgkmcnt(0)" ::: "memory");  // wave's P visible
#pragma unroll
    for (int m = 0; m < 2; ++m) {
      short8 pa = *(const short8*)&Pme[c * 64 + (((m * 4 + quad) ^ c7) * 8)];
#pragma unroll
      for (int nj = 0; nj < 4; ++nj) {
        short8 bvv = *(const short8*)&Vc[(nj * 16 + c) * 64 +
                                         (((m * 4 + quad) ^ c7) * 8)];
        oacc[nj] = MFMA(pa, bvv, oacc[nj]);
      }
    }
    __syncthreads();  // drains prefetch AFTER compute
  }
  // ---- combine O across key halves (Osh overlays Klds buf0, now dead) ----
  float* Osh = (float*)Klds;  // [64][64] f32 = 16 KB
  if (kh == 1) {
#pragma unroll
    for (int nj = 0; nj < 4; ++nj)
#pragma unroll
      for (int r = 0; r < 4; ++r)
        Osh[(qsub * 16 + quad * 4 + r) * 64 + nj * 16 + c] = oacc[nj][r];
  }
  __syncthreads();
  if (kh == 0) {
#pragma unroll
    for (int nj = 0; nj < 4; ++nj)
#pragma unroll
      for (int r = 0; r < 4; ++r) {
        float v =
            oacc[nj][r] + Osh[(qsub * 16 + quad * 4 + r) * 64 + nj * 16 + c];
        Ob[(size_t)(rbase + qsub * 16 + quad * 4 + r) * 512 + h * 64 +
           nj * 16 + c] = f2bf(v);
      }
  }
}

// ---------------------------------------------------------------------------
extern "C" void kernel_launch(void* const* d_in, const int* in_sizes, int n_in,
                              void* d_out, int out_size, void* d_ws, size_t ws_size,
                              hipStream_t stream) {
  const float* x  = (const float*)d_in[0];
  const float* Wq = (const float*)d_in[1];
  const float* bq = (const float*)d_in[2];
  const float* Wk = (const float*)d_in[3];
  const float* bk = (const float*)d_in[4];
  const float* Wv = (const float*)d_in[5];
  const float* bv = (const float*)d_in[6];
  const float* Wo = (const float*)d_in[7];
  const float* bo = (const float*)d_in[8];

  float* out0 = (float*)d_out;                  // [2,2048,512] fp32
  float* attn = out0 + (size_t)2 * 2048 * 512;  // [2,8,2048,2048] fp32

  uint8_t* ws = (uint8_t*)d_ws;
  uint16_t* xb  = (uint16_t*)(ws);              // 4 MB
  uint16_t* W3  = (uint16_t*)(ws + 0x400000);   // 1.5 MB (Wq|Wk|Wv rows)
  uint16_t* Wob = (uint16_t*)(ws + 0x580000);   // 0.5 MB
  uint16_t* Qb  = (uint16_t*)(ws + 0x600000);   // 4 MB [4096][512]
  uint16_t* Kb  = (uint16_t*)(ws + 0xA00000);   // 4 MB [4096][512]
  uint16_t* Vt  = (uint16_t*)(ws + 0xE00000);   // 4 MB [b*512+h*64+d][2048]
  uint16_t* Ob  = (uint16_t*)(ws + 0x1200000);  // 4 MB [4096][512]
  float*    rq  = (float*)  (ws + 0x1600000);   // 128 KB [4096*8]

  static bool attr_set = false;
  if (!attr_set) {
    hipFuncSetAttribute((const void*)attn_kernel,
                        hipFuncAttributeMaxDynamicSharedMemorySize, 81920);
    attr_set = true;
  }

  convert_kernel<<<2048, 256, 0, stream>>>(x, Wq, Wk, Wv, Wo, xb, W3, Wob);
  qkv_gemm<<<dim3(12, 64), 256, 0, stream>>>(xb, W3, bq, bk, bv, Qb, Kb, Vt, rq);
  attn_kernel<<<512, 512, 81920, stream>>>(Qb, Kb, Vt, rq, attn, Ob);
  proj_gemm<<<dim3(8, 64), 256, 0, stream>>>(Ob, Wob, bo, out0);
}